// Round 1
// baseline (1072.825 us; speedup 1.0000x reference)
//
#include <hip/hip_runtime.h>

#define B_IN   8
#define C_CH   64
#define H_IN   200
#define W_IN   320
#define H_OUT  48
#define W_OUT  320
#define N_BOX  256

__global__ __launch_bounds__(W_OUT) void roi_crop_kernel(
    const float* __restrict__ x,
    const int*   __restrict__ bboxes,
    const int*   __restrict__ box_img,
    float*       __restrict__ out)
{
    const int i   = blockIdx.x;   // output row   0..47
    const int box = blockIdx.y;   // box          0..255
    const int j   = threadIdx.x;  // output col   0..319

    int x0 = bboxes[box * 4 + 0];
    int y0 = bboxes[box * 4 + 1];
    int x1 = bboxes[box * 4 + 2];
    int y1 = bboxes[box * 4 + 3];

    x0 = min(max(x0, 0), W_IN - 1);
    y0 = min(max(y0, 0), H_IN - 1);
    x1 = min(max(x1, 0), W_IN - 1);
    y1 = min(max(y1, 0), H_IN - 1);
    x1 = max(x1, x0);
    y1 = max(y1, y0);

    const int h = y1 - y0 + 1;
    const int w = x1 - x0 + 1;

    const int r   = y0 + (i * h) / H_OUT;   // input row for this output row
    const int col = x0 + (j * w) / W_OUT;   // input col for this output col
    const int img = box_img[box];

    // input:  x[((img*C + c)*H_IN + r)*W_IN + col]
    // output: out[((box*C + c)*H_OUT + i)*W_OUT + j]
    const float* __restrict__ src =
        x + (size_t)img * (C_CH * H_IN * W_IN) + (size_t)r * W_IN + col;
    float* __restrict__ dst =
        out + (size_t)box * (C_CH * H_OUT * W_OUT) + (size_t)i * W_OUT + j;

    #pragma unroll 8
    for (int c = 0; c < C_CH; ++c) {
        dst[(size_t)c * (H_OUT * W_OUT)] = src[(size_t)c * (H_IN * W_IN)];
    }
}

extern "C" void kernel_launch(void* const* d_in, const int* in_sizes, int n_in,
                              void* d_out, int out_size, void* d_ws, size_t ws_size,
                              hipStream_t stream) {
    const float* x       = (const float*)d_in[0];
    const int*   bboxes  = (const int*)d_in[1];
    const int*   box_img = (const int*)d_in[2];
    float*       out     = (float*)d_out;

    dim3 grid(H_OUT, N_BOX);   // (48, 256)
    dim3 block(W_OUT);         // 320 threads
    roi_crop_kernel<<<grid, block, 0, stream>>>(x, bboxes, box_img, out);
}